// Round 1
// baseline (144.002 us; speedup 1.0000x reference)
//
#include <hip/hip_runtime.h>
#include <math.h>

#define H 512
#define W 512
#define BAND 8
#define NQ 11   // 0:s0(mask) 1-4:s1i..s4i 5-8:s1o..s4o 9:tex 10:shape

__device__ __forceinline__ float shfl_up1(float v, int lane) {
    float r = __shfl_up(v, 1);
    return (lane == 0) ? 0.0f : r;
}
__device__ __forceinline__ float shfl_dn1(float v, int lane) {
    float r = __shfl_down(v, 1);
    return (lane == 63) ? 0.0f : r;
}

__device__ __forceinline__ void load_row(const float* __restrict__ base, size_t img_off,
                                         int y, int x0, float* dst) {
    if (y < 0 || y >= H) {
        #pragma unroll
        for (int j = 0; j < 8; j++) dst[j] = 0.0f;
    } else {
        const float4* p = reinterpret_cast<const float4*>(base + img_off + (size_t)y * W + x0);
        float4 a = p[0];
        float4 b = p[1];
        dst[0] = a.x; dst[1] = a.y; dst[2] = a.z; dst[3] = a.w;
        dst[4] = b.x; dst[5] = b.y; dst[6] = b.z; dst[7] = b.w;
    }
}

// Given 3-row window (P,C,N) of 8 columns per lane (wave spans full 512-wide row),
// compute 3x3 zero-padded local variance and 5-point Laplacian for the center row.
__device__ __forceinline__ void process_rows(const float* P, const float* C, const float* N,
                                             int lane, float* tvar, float* lap) {
    float c1[8], c2[8];
    #pragma unroll
    for (int j = 0; j < 8; j++) {
        c1[j] = P[j] + C[j] + N[j];
        c2[j] = P[j]*P[j] + C[j]*C[j] + N[j]*N[j];
    }
    // horizontal halos via cross-lane shuffle; lane0/lane63 edges are true zero padding
    float c1l = shfl_up1(c1[7], lane), c1r = shfl_dn1(c1[0], lane);
    float c2l = shfl_up1(c2[7], lane), c2r = shfl_dn1(c2[0], lane);
    float Cl  = shfl_up1(C[7],  lane), Cr  = shfl_dn1(C[0],  lane);
    const float inv9 = 1.0f / 9.0f;
    #pragma unroll
    for (int j = 0; j < 8; j++) {
        float l1 = (j == 0) ? c1l : c1[j-1];
        float r1 = (j == 7) ? c1r : c1[j+1];
        float l2 = (j == 0) ? c2l : c2[j-1];
        float r2 = (j == 7) ? c2r : c2[j+1];
        float s1 = l1 + c1[j] + r1;     // 3x3 box sum of x
        float s2 = l2 + c2[j] + r2;     // 3x3 box sum of x^2
        float mn = s1 * inv9;
        tvar[j] = s2 * inv9 - mn * mn;  // E[x^2]-E[x]^2 over padded window
        float cl = (j == 0) ? Cl : C[j-1];
        float cr = (j == 7) ? Cr : C[j+1];
        lap[j] = (c1[j] - C[j]) + cl + cr - 4.0f * C[j];  // up+down+left+right-4c
    }
}

__global__ __launch_bounds__(256) void radiomics_main(
    const float* __restrict__ inp, const float* __restrict__ outp,
    const float* __restrict__ mask, double* __restrict__ partials)
{
    const int tid = threadIdx.x;
    const int lane = tid & 63;
    const int wib = tid >> 6;                    // wave in block (0..3)
    const int gwave = blockIdx.x * 4 + wib;
    const int bands_per_img = H / BAND;          // 64
    const int b = gwave / bands_per_img;
    const int band = gwave - b * bands_per_img;
    const int y0 = band * BAND;
    const size_t off = (size_t)b * H * W;
    const int x0 = lane * 8;

    float Pi[8], Ci[8], Ni[8];
    float Po[8], Co[8], No[8];
    float Mk[8];

    load_row(inp,  off, y0 - 1, x0, Pi);
    load_row(inp,  off, y0,     x0, Ci);
    load_row(inp,  off, y0 + 1, x0, Ni);
    load_row(outp, off, y0 - 1, x0, Po);
    load_row(outp, off, y0,     x0, Co);
    load_row(outp, off, y0 + 1, x0, No);
    load_row(mask, off, y0,     x0, Mk);

    float acc[NQ];
    #pragma unroll
    for (int q = 0; q < NQ; q++) acc[q] = 0.0f;

    #pragma unroll
    for (int i = 0; i < BAND; i++) {
        const int y = y0 + i;
        // prefetch next iteration's rows before this row's compute
        float NNi[8], NNo[8], NM[8];
        load_row(inp,  off, y + 2, x0, NNi);
        load_row(outp, off, y + 2, x0, NNo);
        load_row(mask, off, y + 1, x0, NM);

        float tvi[8], lpi[8], tvo[8], lpo[8];
        process_rows(Pi, Ci, Ni, lane, tvi, lpi);
        process_rows(Po, Co, No, lane, tvo, lpo);

        #pragma unroll
        for (int j = 0; j < 8; j++) {
            float m = Mk[j];
            acc[9]  += fabsf(tvo[j] * m - tvi[j] * m);
            acc[10] += fabsf(lpo[j] * m - lpi[j] * m);
            acc[0]  += m;
            float xi = Ci[j];
            float t = xi * m; acc[1] += t; t *= xi; acc[2] += t; t *= xi; acc[3] += t; t *= xi; acc[4] += t;
            float xo = Co[j];
            t = xo * m; acc[5] += t; t *= xo; acc[6] += t; t *= xo; acc[7] += t; t *= xo; acc[8] += t;
        }
        #pragma unroll
        for (int j = 0; j < 8; j++) {
            Pi[j] = Ci[j]; Ci[j] = Ni[j]; Ni[j] = NNi[j];
            Po[j] = Co[j]; Co[j] = No[j]; No[j] = NNo[j];
            Mk[j] = NM[j];
        }
    }

    // wave-level fp32 reduce, then fp64 per-block partial (no global atomics)
    #pragma unroll
    for (int q = 0; q < NQ; q++) {
        float v = acc[q];
        #pragma unroll
        for (int o = 32; o > 0; o >>= 1) v += __shfl_down(v, o);
        acc[q] = v;
    }
    __shared__ double red[4][NQ];
    if (lane == 0) {
        #pragma unroll
        for (int q = 0; q < NQ; q++) red[wib][q] = (double)acc[q];
    }
    __syncthreads();
    if (tid < NQ) {
        double s = red[0][tid] + red[1][tid] + red[2][tid] + red[3][tid];
        partials[(size_t)blockIdx.x * NQ + tid] = s;
    }
}

__global__ __launch_bounds__(64) void radiomics_final(
    const double* __restrict__ partials, int nblk, float* __restrict__ out4, double inv_n)
{
    const int lane = threadIdx.x;
    double q[NQ];
    #pragma unroll
    for (int k = 0; k < NQ; k++) {
        double s = 0.0;
        for (int i = lane; i < nblk; i += 64) s += partials[(size_t)i * NQ + k];
        #pragma unroll
        for (int o = 32; o > 0; o >>= 1) s += __shfl_down(s, o);
        q[k] = s;
    }
    if (lane == 0) {
        const double EPS = 1e-8;
        double S0 = q[0];
        double ms = S0 + EPS;
        double im = q[1] / ms, om = q[5] / ms;
        double im2 = im * im, im3 = im2 * im, im4 = im2 * im2;
        double om2 = om * om, om3 = om2 * om, om4 = om2 * om2;
        double di2 = q[2] - 2.0*im*q[1] + im2*S0;
        double do2 = q[6] - 2.0*om*q[5] + om2*S0;
        double iv = di2 / ms, ov = do2 / ms;
        double di3 = q[3] - 3.0*im*q[2] + 3.0*im2*q[1] - im3*S0;
        double do3 = q[7] - 3.0*om*q[6] + 3.0*om2*q[5] - om3*S0;
        double isk = di3 / (ms * (iv * sqrt(iv) + EPS));
        double osk = do3 / (ms * (ov * sqrt(ov) + EPS));
        double di4 = q[4] - 4.0*im*q[3] + 6.0*im2*q[2] - 4.0*im3*q[1] + im4*S0;
        double do4 = q[8] - 4.0*om*q[7] + 6.0*om2*q[6] - 4.0*om3*q[5] + om4*S0;
        double iku = di4 / (ms * (iv * iv + EPS));
        double oku = do4 / (ms * (ov * ov + EPS));
        double intensity = (im-om)*(im-om) + (iv-ov)*(iv-ov)
                         + (isk-osk)*(isk-osk) + (iku-oku)*(iku-oku);
        double texture = q[9]  * inv_n;
        double shape   = q[10] * inv_n;
        // TEXTURE_W=1.0, SHAPE_W=0.5, INTENSITY_W=1.0
        double total = intensity + texture + 0.5 * shape;
        out4[0] = (float)intensity;
        out4[1] = (float)texture;
        out4[2] = (float)shape;
        out4[3] = (float)total;
    }
}

extern "C" void kernel_launch(void* const* d_in, const int* in_sizes, int n_in,
                              void* d_out, int out_size, void* d_ws, size_t ws_size,
                              hipStream_t stream) {
    const float* inp  = (const float*)d_in[0];
    const float* outp = (const float*)d_in[1];
    const float* mask = (const float*)d_in[2];
    const int total = in_sizes[0];             // 32*1*512*512
    const int nimg  = total / (H * W);         // 32
    const int nwaves = nimg * (H / BAND);      // 2048
    const int nblk   = nwaves / 4;             // 512 blocks of 256 threads
    double* partials = (double*)d_ws;          // nblk*NQ doubles, fully overwritten

    radiomics_main<<<nblk, 256, 0, stream>>>(inp, outp, mask, partials);
    const double inv_n = 1.0 / (double)total;
    radiomics_final<<<1, 64, 0, stream>>>(partials, nblk, (float*)d_out, inv_n);
}